// Round 10
// baseline (734.653 us; speedup 1.0000x reference)
//
#include <hip/hip_runtime.h>
#include <math.h>

// SparseDiffAttn: B=1, H=12, S=3840, D=128, BM=192 (QG=20), topk=1024.
// R20: (1) sparse_attn PV re-split 32q x 4dt per wave: V b128 reads halve
// (16->8; they were 12x-redundant across waves on the binding LDS pipe);
// P becomes cross-wave -> +1 barrier/tile with explicit lgkmcnt(0) flush,
// and rl exchanged once at end via rls_sm. Per-fragment MFMA chains, P/V
// values, l, rl, products all BIT-IDENTICAL -> absmax must stay exactly
// 0.0009765625. (2) argmin launch deleted: exact_rl/exact_pair replicate
// the deterministic argmin reduction (same tie-break). (3) presplit stores
// merged to 16B. stats/colsum/topk3 unchanged from R16 (pinned at 59-60%
// MfmaUtil across 6 schedule variants).

#define HH 12
#define SS 3840
#define DD 128
#define QGn 20
#define TKn 1024
#define NROWS (HH * QGn)
#define HS (HH * SS)
#define NT 60            // 64-row tiles per head
#define TCH 3072         // 16B chunks per tile (64 rows x 128 dims x 3 comps)
#define SCALE_D 0.08838834764831845
#define SCALE_F 0.08838834764831845f

typedef short short8 __attribute__((ext_vector_type(8)));
typedef short short4v __attribute__((ext_vector_type(4)));
typedef float f32x4 __attribute__((ext_vector_type(4)));

#define MFMA(a, b, c) __builtin_amdgcn_mfma_f32_16x16x32_bf16(a, b, c, 0, 0, 0)
#define MFMA_B16(c, a, b) \
  c = __builtin_amdgcn_mfma_f32_16x16x32_bf16(a, b, c, 0, 0, 0)

typedef __attribute__((address_space(3))) unsigned int lds_u32;
typedef const __attribute__((address_space(1))) unsigned int glb_u32;

__device__ __forceinline__ unsigned short bf_rne(float x) {
  unsigned u = __float_as_uint(x);
  u = (u + 0x7fffu + ((u >> 16) & 1u)) >> 16;
  return (unsigned short)u;
}
__device__ __forceinline__ float bf_f(unsigned short b) {
  return __uint_as_float(((unsigned)b) << 16);
}
__device__ __forceinline__ void split3(float f, unsigned short& a,
                                       unsigned short& b, unsigned short& c) {
  a = bf_rne(f);
  float r = f - bf_f(a);
  b = bf_rne(r);
  r = r - bf_f(b);
  c = bf_rne(r);
}
__device__ __forceinline__ void split2(float f, unsigned short& a,
                                       unsigned short& b) {
  a = bf_rne(f);
  float r = f - bf_f(a);
  b = bf_rne(r);
}
__device__ __forceinline__ short8 ldfrag(const unsigned short* base, int chunk) {
  return *(const short8*)&base[(size_t)chunk * 8];
}

// ---------------------------------------------------------------------------
// Kernel 0: presplit Q,K -> bf16 triples in fragment-chunk layout.
// R20: paired ushort4 stores merged into aligned 16B stores.
// ---------------------------------------------------------------------------
__global__ __launch_bounds__(1024) void presplit_kernel(
    const float* __restrict__ q, const float* __restrict__ k,
    unsigned short* __restrict__ qsplit, unsigned short* __restrict__ ksplit) {
  const int t = threadIdx.x;
  const int lane = t & 63;
  const int u = t >> 6;
  const int kc = u & 3, kt = u >> 2;
  const int ln = lane & 15, quad = lane >> 4;
  const int c = blockIdx.x;
  const int h = blockIdx.y;
  const float* src = blockIdx.z ? k : q;
  unsigned short* dst = blockIdx.z ? ksplit : qsplit;

  const float* p =
      &src[(size_t)(h * SS + c * 64 + kt * 16 + ln) * DD + kc * 32 + quad * 8];
  float b8[8];
  *(float4*)&b8[0] = *(const float4*)&p[0];
  *(float4*)&b8[4] = *(const float4*)&p[4];
  __attribute__((aligned(16))) unsigned short f0[8], f1[8], f2[8];
#pragma unroll
  for (int e = 0; e < 8; ++e) split3(b8[e], f0[e], f1[e], f2[e]);
  size_t base =
      ((size_t)(h * NT + c) * TCH + ((kt * 4 + kc) * 3) * 64 + lane) * 8;
  *(uint4*)&dst[base + 0] = *(const uint4*)f0;
  *(uint4*)&dst[base + 512] = *(const uint4*)f1;        // cm=1: +64 chunks
  *(uint4*)&dst[base + 1024] = *(const uint4*)f2;       // cm=2: +128 chunks
}

// ---------------------------------------------------------------------------
// Kernel 1: partial softmax denominators. R16 structure (3-slot single-barrier
// tail-deferred pipeline), unchanged.
// ---------------------------------------------------------------------------
__global__ __launch_bounds__(256) void stats_mfma(
    const unsigned short* __restrict__ qsplit,
    const unsigned short* __restrict__ ksplit,
    double* __restrict__ lpart) {
  __shared__ __align__(16) unsigned short Bs[3][6144];  // 3 x 12 KiB slots
  const int t = threadIdx.x;
  const int w = t >> 6;
  const int lane = t & 63;
  const int ln = lane & 15;
  const int quad = lane >> 4;
  const int h = blockIdx.y;
  const int nq = blockIdx.z;
  const int q0 = blockIdx.x * 128 + w * 32;
  const int tq = blockIdx.x * 2 + (w >> 1);
  const int ktA = (w & 1) * 2;

  short8 A[2][4][3];
  {
    const unsigned short* qb = &qsplit[(size_t)(h * NT + tq) * TCH * 8];
#pragma unroll
    for (int s = 0; s < 2; ++s)
#pragma unroll
      for (int kc = 0; kc < 4; ++kc)
#pragma unroll
        for (int cm = 0; cm < 3; ++cm)
          A[s][kc][cm] =
              ldfrag(qb, (((ktA + s) * 4 + kc) * 3 + cm) * 64 + lane);
  }

  double racc[2][4];
#pragma unroll
  for (int s = 0; s < 2; ++s)
#pragma unroll
    for (int r = 0; r < 4; ++r) racc[s][r] = 0.0;

  // Quarter's key stream: 60 contiguous 12KB 16-key sub-tiles.
  // j = (c - nq*15)*4 + kt, same order as R10-R19 (bit-identical).
  const unsigned short* kq = &ksplit[(size_t)(h * NT + nq * 15) * TCH * 8];

#define STG_S(slot, j)                                                     \
  do {                                                                     \
    const unsigned short* src_ = kq + (size_t)(j) * 6144 + t * 8;          \
    __builtin_amdgcn_global_load_lds((glb_u32*)(src_),                     \
        (lds_u32*)&Bs[slot][w * 512], 16, 0, 0);                           \
    __builtin_amdgcn_global_load_lds((glb_u32*)(src_ + 2048),              \
        (lds_u32*)&Bs[slot][2048 + w * 512], 16, 0, 0);                    \
    __builtin_amdgcn_global_load_lds((glb_u32*)(src_ + 4096),              \
        (lds_u32*)&Bs[slot][4096 + w * 512], 16, 0, 0);                    \
  } while (0)

  const f32x4 z = {0.f, 0.f, 0.f, 0.f};
  f32x4 C[2][3];  // holds step j-1's scores at the top of step j

  // Prologue: tile 0 in flight.
  STG_S(0, 0);

  int cur = 0;
#pragma unroll 1
  for (int j = 0; j < 60; ++j) {
    __builtin_amdgcn_sched_barrier(0);
    if (j < 59) {
      const int nxt = (cur == 2) ? 0 : cur + 1;
      STG_S(nxt, j + 1);
      asm volatile("s_waitcnt vmcnt(3)" ::: "memory");  // own tile-j loads done
    } else {
      asm volatile("s_waitcnt vmcnt(0)" ::: "memory");
    }
    __builtin_amdgcn_s_barrier();  // all waves drained own tile-j loads
    __builtin_amdgcn_sched_barrier(0);
    __builtin_amdgcn_s_setprio(1);
    if (j > 0) {
      // deferred tail of step j-1 (same values, same racc order)
#pragma unroll
      for (int s = 0; s < 2; ++s)
#pragma unroll
        for (int r = 0; r < 4; ++r) {
          float sv = (C[s][0][r] + C[s][1][r]) + C[s][2][r];
          racc[s][r] += (double)__expf(sv * SCALE_F);
        }
    }
    const unsigned short* Bp = &Bs[cur][0];
#pragma unroll
    for (int kc = 0; kc < 4; ++kc) {
      short8 B0 = *(const short8*)&Bp[(kc * 3 + 0) * 512 + lane * 8];
      short8 B1 = *(const short8*)&Bp[(kc * 3 + 1) * 512 + lane * 8];
      short8 B2 = *(const short8*)&Bp[(kc * 3 + 2) * 512 + lane * 8];
#pragma unroll
      for (int s = 0; s < 2; ++s) {
        if (kc == 0) {
          C[s][0] = MFMA(A[s][0][0], B0, z);         // == 0 + A0B0
          C[s][1] = MFMA(A[s][0][0], B1, z);         // == 0 + A0B1
          C[s][1] = MFMA(A[s][0][1], B0, C[s][1]);
          C[s][0] = MFMA(A[s][0][1], B1, C[s][0]);
          C[s][2] = MFMA(A[s][0][2], B0, z);         // == 0 + A2B0
          C[s][2] = MFMA(A[s][0][0], B2, C[s][2]);
        } else {
          MFMA_B16(C[s][0], A[s][kc][0], B0);
          MFMA_B16(C[s][1], A[s][kc][0], B1);
          MFMA_B16(C[s][1], A[s][kc][1], B0);
          MFMA_B16(C[s][0], A[s][kc][1], B1);
          MFMA_B16(C[s][2], A[s][kc][2], B0);
          MFMA_B16(C[s][2], A[s][kc][0], B2);
        }
      }
    }
    __builtin_amdgcn_s_setprio(0);
    cur = (cur == 2) ? 0 : cur + 1;  // no end barrier: 3-slot rotation is safe
  }
#undef STG_S

  // final tail (step 59)
#pragma unroll
  for (int s = 0; s < 2; ++s)
#pragma unroll
    for (int r = 0; r < 4; ++r) {
      float sv = (C[s][0][r] + C[s][1][r]) + C[s][2][r];
      racc[s][r] += (double)__expf(sv * SCALE_F);
    }

#pragma unroll
  for (int s = 0; s < 2; ++s)
#pragma unroll
    for (int r = 0; r < 4; ++r) {
      double v = racc[s][r];
      v += __shfl_xor(v, 1);
      v += __shfl_xor(v, 2);
      v += __shfl_xor(v, 4);
      v += __shfl_xor(v, 8);
      if (ln == 0)
        lpart[(size_t)nq * HS + h * SS + q0 + s * 16 + quad * 4 + r] = v;
    }
}

// ---------------------------------------------------------------------------
// Kernel 2: bs colsums. R16 structure (3-slot single-barrier), unchanged.
// ---------------------------------------------------------------------------
__global__ __launch_bounds__(256) void colsum_mfma(
    const unsigned short* __restrict__ qsplit,
    const unsigned short* __restrict__ ksplit,
    const double* __restrict__ lpart, double* __restrict__ bs) {
  __shared__ double rls[192];
  __shared__ __align__(16) unsigned short As[3][6144];  // 3 x 12 KiB slots
  const int t = threadIdx.x;
  const int w = t >> 6;
  const int lane = t & 63;
  const int ln = lane & 15;
  const int quad = lane >> 4;
  const int h = blockIdx.z, g = blockIdx.y;
  const int k0 = blockIdx.x * 128 + w * 32;
  const int tk = blockIdx.x * 2 + (w >> 1);
  const int ktB = (w & 1) * 2;

  short8 Bk[2][4][3];
  {
    const unsigned short* kb = &ksplit[(size_t)(h * NT + tk) * TCH * 8];
#pragma unroll
    for (int s = 0; s < 2; ++s)
#pragma unroll
      for (int kc = 0; kc < 4; ++kc)
#pragma unroll
        for (int cm = 0; cm < 3; ++cm)
          Bk[s][kc][cm] =
              ldfrag(kb, (((ktB + s) * 4 + kc) * 3 + cm) * 64 + lane);
  }

  if (t < 192) {
    size_t qi = h * SS + g * 192 + t;
    rls[t] = 1.0 / (lpart[qi] + lpart[HS + qi] + lpart[2 * (size_t)HS + qi] +
                    lpart[3 * (size_t)HS + qi]);
  }
  __syncthreads();  // rls visible to all waves before staging loop

  double cacc[2] = {0.0, 0.0};

  // Group's query stream: 12 contiguous 12KB 16-query sub-tiles.
  // j = qc*4 + qt, same order as R10-R19 (bit-identical); qrow = 16*j.
  const unsigned short* qg = &qsplit[(size_t)(h * NT + g * 3) * TCH * 8];

#define STG_C(slot, j)                                                     \
  do {                                                                     \
    const unsigned short* src_ = qg + (size_t)(j) * 6144 + t * 8;          \
    __builtin_amdgcn_global_load_lds((glb_u32*)(src_),                     \
        (lds_u32*)&As[slot][w * 512], 16, 0, 0);                           \
    __builtin_amdgcn_global_load_lds((glb_u32*)(src_ + 2048),              \
        (lds_u32*)&As[slot][2048 + w * 512], 16, 0, 0);                    \
    __builtin_amdgcn_global_load_lds((glb_u32*)(src_ + 4096),              \
        (lds_u32*)&As[slot][4096 + w * 512], 16, 0, 0);                    \
  } while (0)

  const f32x4 z = {0.f, 0.f, 0.f, 0.f};
  f32x4 C[2][3];  // holds step j-1's scores at the top of step j

  // Prologue: tile 0 in flight.
  STG_C(0, 0);

  int cur = 0;
#pragma unroll 1
  for (int j = 0; j < 12; ++j) {
    __builtin_amdgcn_sched_barrier(0);
    if (j < 11) {
      const int nxt = (cur == 2) ? 0 : cur + 1;
      STG_C(nxt, j + 1);
      asm volatile("s_waitcnt vmcnt(3)" ::: "memory");  // own tile-j loads done
    } else {
      asm volatile("s_waitcnt vmcnt(0)" ::: "memory");
    }
    __builtin_amdgcn_s_barrier();
    __builtin_amdgcn_sched_barrier(0);
    __builtin_amdgcn_s_setprio(1);
    if (j > 0) {
      const int qprev = (j - 1) * 16;  // tail of step j-1
#pragma unroll
      for (int s = 0; s < 2; ++s)
#pragma unroll
        for (int r = 0; r < 4; ++r) {
          float p = __expf(((C[s][0][r] + C[s][1][r]) + C[s][2][r]) * SCALE_F);
          cacc[s] += (double)p * rls[qprev + quad * 4 + r];
        }
    }
    const unsigned short* Ap = &As[cur][0];
#pragma unroll
    for (int kc = 0; kc < 4; ++kc) {
      short8 A0 = *(const short8*)&Ap[(kc * 3 + 0) * 512 + lane * 8];
      short8 A1 = *(const short8*)&Ap[(kc * 3 + 1) * 512 + lane * 8];
      short8 A2 = *(const short8*)&Ap[(kc * 3 + 2) * 512 + lane * 8];
#pragma unroll
      for (int s = 0; s < 2; ++s) {
        if (kc == 0) {
          C[s][0] = MFMA(A0, Bk[s][0][0], z);        // == 0 + A0Bk0
          C[s][1] = MFMA(A1, Bk[s][0][0], z);        // == 0 + A1Bk0
          C[s][1] = MFMA(A0, Bk[s][0][1], C[s][1]);
          C[s][0] = MFMA(A1, Bk[s][0][1], C[s][0]);
          C[s][2] = MFMA(A2, Bk[s][0][0], z);        // == 0 + A2Bk0
          C[s][2] = MFMA(A0, Bk[s][0][2], C[s][2]);
        } else {
          MFMA_B16(C[s][0], A0, Bk[s][kc][0]);
          MFMA_B16(C[s][1], A1, Bk[s][kc][0]);
          MFMA_B16(C[s][1], A0, Bk[s][kc][1]);
          MFMA_B16(C[s][0], A1, Bk[s][kc][1]);
          MFMA_B16(C[s][2], A2, Bk[s][kc][0]);
          MFMA_B16(C[s][2], A0, Bk[s][kc][2]);
        }
      }
    }
    __builtin_amdgcn_s_setprio(0);
    cur = (cur == 2) ? 0 : cur + 1;  // no end barrier
  }
#undef STG_C

  // final tail (step 11, qrow = 176)
#pragma unroll
  for (int s = 0; s < 2; ++s)
#pragma unroll
    for (int r = 0; r < 4; ++r) {
      float p = __expf(((C[s][0][r] + C[s][1][r]) + C[s][2][r]) * SCALE_F);
      cacc[s] += (double)p * rls[176 + quad * 4 + r];
    }

#pragma unroll
  for (int s = 0; s < 2; ++s) {
    double v = cacc[s];
    v += __shfl_xor(v, 16);
    v += __shfl_xor(v, 32);
    if (quad == 0)
      bs[(size_t)(h * QGn + g) * SS + k0 + s * 16 + ln] = v;
  }
}

// ---------------------------------------------------------------------------
// Kernel 3: radix top-1024 + boundary capture (R16 parallel suffix-scan,
// unchanged).
// ---------------------------------------------------------------------------
__global__ __launch_bounds__(256) void topk3_kernel(
    const double* __restrict__ bs, int* __restrict__ inds,
    double* __restrict__ bnd_val, int* __restrict__ bnd_idx) {
  __shared__ unsigned long long u[SS];
  __shared__ int hist[256];
  __shared__ int sfx[256];
  __shared__ int s_bin, s_r;
  __shared__ int c_gt, c_eq;
  __shared__ unsigned long long rv[256];
  __shared__ int ri[256];
  const int t = threadIdx.x;
  const int row = blockIdx.x;
  const double* vals = bs + (size_t)row * SS;

  for (int i = t; i < SS; i += 256)
    u[i] = (unsigned long long)__double_as_longlong(vals[i]);

  unsigned long long pref = 0ull;
  int r = TKn;
  for (int shift = 56; shift >= 0; shift -= 8) {
    hist[t] = 0;
    __syncthreads();
    unsigned long long himask =
        (shift == 56) ? 0ull : (0xFFFFFFFFFFFFFFFFull << (shift + 8));
    for (int i = t; i < SS; i += 256) {
      unsigned long long uv = u[i];
      if ((uv & himask) == (pref & himask))
        atomicAdd(&hist[(int)((uv >> shift) & 255)], 1);
    }
    __syncthreads();
    // inclusive suffix scan of hist into sfx (Hillis-Steele, 8 steps)
    sfx[t] = hist[t];
    __syncthreads();
#pragma unroll
    for (int off = 1; off < 256; off <<= 1) {
      int v = (t + off < 256) ? sfx[t + off] : 0;
      __syncthreads();
      sfx[t] += v;
      __syncthreads();
    }
    // serial equivalent: highest bin b with S(b) >= r; s_r = r - S(b+1)
    {
      int St = sfx[t];
      int Sn = (t == 255) ? 0 : sfx[t + 1];
      if (St >= r && Sn < r) {
        s_bin = t;
        s_r = r - Sn;
      }
    }
    if (t == 0) {
      c_gt = 0;
      c_eq = 0;
    }
    __syncthreads();
    pref |= ((unsigned long long)s_bin) << shift;
    r = s_r;
    __syncthreads();
  }
  const int G = TKn - r;
  int* out = inds + (size_t)row * TKn;
  unsigned long long mb = 0ull;
  int mbi = -1;
  for (int i = t; i < SS; i += 256) {
    unsigned long long uv = u[i];
    if (uv > pref) {
      int p = atomicAdd(&c_gt, 1);
      out[p] = i;
    } else if (uv == pref) {
      int e = atomicAdd(&c_eq, 1);
      if (e < r) out[G + e] = i;
      if (e == r - 1) bnd_idx[row * 2 + 0] = i;
    } else if (uv > mb) {
      mb = uv;
      mbi = i;
    }
  }
  rv[t] = mb;
  ri[t] = mbi;
  __syncthreads();
  for (int s2 = 128; s2 > 0; s2 >>= 1) {
    if (t < s2 && rv[t + s2] > rv[t]) {
      rv[t] = rv[t + s2];
      ri[t] = ri[t + s2];
    }
    __syncthreads();
  }
  if (t == 0) {
    bnd_val[row * 2 + 0] = __longlong_as_double((long long)pref);
    bnd_val[row * 2 + 1] = __longlong_as_double((long long)rv[0]);
    bnd_idx[row * 2 + 1] = ri[0];
  }
}

// ---------------------------------------------------------------------------
// exact_rl: R20 — argmin over 240 rows replicated per block (identical
// reduction + tie-break as the deleted argmin_kernel; deterministic).
// ---------------------------------------------------------------------------
__global__ __launch_bounds__(256) void exact_rl_kernel(
    const float* __restrict__ q, const float* __restrict__ k,
    const double* __restrict__ bnd_val, double* __restrict__ rl_exact) {
  __shared__ double gmin[256];
  __shared__ int grow[256];
  __shared__ double qd[DD];
  __shared__ double red[256];
  const int t = threadIdx.x;
  {
    double gv = 1e300;
    int rr = -1;
    if (t < NROWS) {
      gv = bnd_val[t * 2 + 0] - bnd_val[t * 2 + 1];
      rr = t;
    }
    gmin[t] = gv;
    grow[t] = rr;
    __syncthreads();
    for (int s2 = 128; s2 > 0; s2 >>= 1) {
      if (t < s2 && gmin[t + s2] < gmin[t]) {
        gmin[t] = gmin[t + s2];
        grow[t] = grow[t + s2];
      }
      __syncthreads();
    }
  }
  const int row = grow[0];
  const int h = row / QGn, g = row % QGn;
  const float* qp = &q[(size_t)(h * SS + g * 192 + blockIdx.x) * DD];
  if (t < DD) qd[t] = (double)qp[t];
  __syncthreads();
  double l = 0.0;
  for (int kk = t; kk < SS; kk += 256) {
    const float* kp = &k[(size_t)(h * SS + kk) * DD];
    double s = 0.0;
#pragma unroll 4
    for (int d = 0; d < DD; d += 4) {
      float4 kv = *(const float4*)&kp[d];
      s += qd[d] * (double)kv.x + qd[d + 1] * (double)kv.y +
           qd[d + 2] * (double)kv.z + qd[d + 3] * (double)kv.w;
    }
    l += exp(s * SCALE_D);
  }
  red[t] = l;
  __syncthreads();
  for (int s2 = 128; s2 > 0; s2 >>= 1) {
    if (t < s2) red[t] += red[t + s2];
    __syncthreads();
  }
  if (t == 0) rl_exact[blockIdx.x] = 1.0 / red[0];
}

// ---------------------------------------------------------------------------
// exact_pair: R20 — same replicated argmin; kept/drop from bnd_idx directly.
// ---------------------------------------------------------------------------
__global__ __launch_bounds__(256) void exact_pair_kernel(
    const float* __restrict__ q, const float* __restrict__ k,
    const double* __restrict__ bnd_val, const int* __restrict__ bnd_idx,
    const double* __restrict__ rl_exact, int* __restrict__ inds) {
  __shared__ double gmin[256];
  __shared__ int grow[256];
  __shared__ double redX[256], redY[256];
  const int t = threadIdx.x;
  {
    double gv = 1e300;
    int rr = -1;
    if (t < NROWS) {
      gv = bnd_val[t * 2 + 0] - bnd_val[t * 2 + 1];
      rr = t;
    }
    gmin[t] = gv;
    grow[t] = rr;
    __syncthreads();
    for (int s2 = 128; s2 > 0; s2 >>= 1) {
      if (t < s2 && gmin[t + s2] < gmin[t]) {
        gmin[t] = gmin[t + s2];
        grow[t] = grow[t + s2];
      }
      __syncthreads();
    }
  }
  const int row = grow[0];
  const int kept = bnd_idx[row * 2 + 0], drop = bnd_idx[row * 2 + 1];
  const int h = row / QGn, g = row % QGn;
  double px = 0.0, py = 0.0;
  if (t < 192) {
    const float* qp = &q[(size_t)(h * SS + g * 192 + t) * DD];
    const float* kx = &k[(size_t)(h * SS + kept) * DD];
    const float* ky = &k[(size_t)(h * SS + drop) * DD];
    double sx = 0.0, sy = 0.0;
#pragma unroll 4
    for (int d = 0; d < DD; ++d) {
      double qv = (double)qp[d];
      sx += qv * (double)kx[d];
      sy += qv * (double)ky[d];
    }
    double rv = rl_exact[t];
    px = exp(sx * SCALE_D) * rv;
    py = exp(sy * SCALE_D) * rv;
  }
  redX[t] = px;
  redY[t] = py;
  __syncthreads();
  for (int s2 = 128; s2 > 0; s2 >>= 1) {
    if (t < s2) { redX[t] += redX[t + s2]; redY[t] += redY[t + s2]; }
    __syncthreads();
  }
  if (t == 0)
    inds[(size_t)row * TKn + (TKn - 1)] = (redX[0] <= redY[0]) ? kept : drop;
}

// ---------------------------------------------------------------------------
// Kernel 4: MFMA sparse gathered attention. R20: PV re-split — wave w owns
// qsubs {2*(w%6), +1} x dt-half (w/6)*4: V b128 reads halve. P is cross-wave:
// lgkmcnt(0)+barrier between pbuf write (QK phase) and P read (PV phase);
// rl exchanged once at end via rls_sm. Staging identical to R19. All values
// and per-fragment accumulation chains bit-identical.
// ---------------------------------------------------------------------------
__global__ __launch_bounds__(768, 3) void sparse_attn_mfma(
    const float* __restrict__ q, const float* __restrict__ v,
    const int* __restrict__ inds, const unsigned short* __restrict__ ksplit,
    float* __restrict__ out) {
  __shared__ __align__(16) unsigned short ksmN[16 * 512];   // 16 KB
  __shared__ __align__(16) unsigned short vsm[2][128][40];  // 20 KB
  __shared__ __align__(16) unsigned short pbuf[12][2][16][36];  // 27 KB
  __shared__ float rls_sm[12][16];                          // 768 B
  const int t = threadIdx.x;
  const int w = t >> 6;            // 12 waves; waves 0-3 stage
  const int lane = t & 63;
  const int ln = lane & 15;
  const int quad = lane >> 4;
  const int g = blockIdx.x, h = blockIdx.y;
  const int* ip = &inds[(size_t)(h * QGn + g) * TKn];
  const unsigned short* kbh = &ksplit[(size_t)(h * NT) * (TCH * 8)];
  const int qs0 = (w % 6) * 2;     // PV: first owned q-subtile
  const int dtb = (w / 6) * 4;     // PV: dt-half base

  short8 A[4][2];
  {
    const float* qp =
        &q[(size_t)(h * SS + g * 192 + w * 16 + ln) * DD + quad * 8];
#pragma unroll
    for (int kc = 0; kc < 4; ++kc) {
      float b8[8];
      *(float4*)&b8[0] = *(const float4*)&qp[kc * 32];
      *(float4*)&b8[4] = *(const float4*)&qp[kc * 32 + 4];
      short8 f0, f1;
#pragma unroll
      for (int e = 0; e < 8; ++e) {
        unsigned short x0, x1;
        split2(b8[e], x0, x1);
        f0[e] = (short)x0; f1[e] = (short)x1;
      }
      A[kc][0] = f0; A[kc][1] = f1;
    }
  }

  f32x4 Oa[4], Ob[4];
#pragma unroll
  for (int d2 = 0; d2 < 4; ++d2) {
    Oa[d2] = (f32x4){0.f, 0.f, 0.f, 0.f};
    Ob[d2] = (f32x4){0.f, 0.f, 0.f, 0.f};
  }
  float lacc[4] = {0.f, 0.f, 0.f, 0.f};

  const int kk = t >> 3;   // staging V row (valid for t < 256)
  const int sub = t & 7;
  const int sW = w >> 1;   // staging K subtile (waves 0-3)
  const int c0 = w * 4;    // first K chunk staged by this wave

  // Prologue (staging waves only): tile-0 staging key + V rows into regs.
  int gkA = 0;
  float4 rv4[4];
  if (w < 4) {
    gkA = ip[sW * 16 + ln];
    int gkV = ip[kk];
    const float* vp = &v[(size_t)(h * SS + gkV) * DD + sub * 16];
#pragma unroll
    for (int e4 = 0; e4 < 4; ++e4) rv4[e4] = *(const float4*)&vp[e4 * 4];
  }

  for (int kt = 0; kt < TKn; kt += 32) {
    __builtin_amdgcn_s_barrier();      // b1: prev tile's LDS reads retired
    __builtin_amdgcn_sched_barrier(0);
    if (w < 4) {
      const bool more = (kt + 32 < TKn);
      int gkVn = 0, gkAn = 0;
      if (more) {
        gkVn = ip[kt + 32 + kk];              // next-tile V row
        gkAn = ip[kt + 32 + sW * 16 + ln];    // next-tile staging key
      }
      // K fragment staging: ksplit -> LDS, per-lane src, lane-linear dest.
      {
        const unsigned short* rowp = kbh + (size_t)(gkA >> 6) * (TCH * 8) +
                                     ((gkA & 15) + 16 * quad) * 8;
        const int ktile = (gkA >> 4) & 3;
#pragma unroll
        for (int i = 0; i < 4; ++i) {
          const int c16 = c0 + i;
          const int kc = (c16 >> 1) & 3;
          const int cm = c16 & 1;
          __builtin_amdgcn_global_load_lds(
              (glb_u32*)(rowp + ((ktile * 4 + kc) * 3 + cm) * 512),
              (lds_u32*)&ksmN[c16 * 512], 16, 0, 0);
        }
      }
      // V write from prefetched regs (split2 values identical).
#pragma unroll
      for (int e4 = 0; e4 < 4; ++e4) {
        float4 vv = rv4[e4];
        ushort4 v0, v1;
        split2(vv.x, v0.x, v1.x);
        split2(vv.y, v0.y, v1.y);
        split2(vv.z, v0.z, v1.z);
        split2(vv.w, v0.w, v1.w);
        int d0 = sub * 16 + e4 * 4;
        vsm[0][d0 + 0][kk] = v0.x; vsm[1][d0 + 0][kk] = v1.x;
        vsm[0][d0 + 1][kk] = v0.y; vsm[1][d0 + 1][kk] = v1.y;
        vsm[0][d0 + 2][kk] = v0.z; vsm[1][d0 + 2][kk] = v1.z;
        vsm[0][d0 + 3][kk] = v0.w; vsm[1][d0 + 3][kk] = v1.w;
      }
      // Issue next tile's V gather; counted wait keeps it in flight.
      if (more) {
        const float* vp = &v[(size_t)(h * SS + gkVn) * DD + sub * 16];
#pragma unroll
        for (int e4 = 0; e4 < 4; ++e4) rv4[e4] = *(const float4*)&vp[e4 * 4];
        asm volatile("s_waitcnt vmcnt(4) lgkmcnt(0)" ::: "memory");
        gkA = gkAn;
      } else {
        asm volatile("s_waitcnt vmcnt(0) lgkmcnt(0)" ::: "memory");
      }
    }
    __builtin_amdgcn_s_barrier();      // b2: ksmN + vsm staged, all 12 waves
    __builtin_amdgcn_sched_barrier(0);

    // ---- QK phase (wave w owns q-subtile w; unchanged) ----
#pragma unroll
    for (int s = 0; s < 2; ++s) {
      f32x4 C0 = {0.f, 0.f, 0.f, 0.f};
      f32x4 C1 = C0;
      __builtin_amdgcn_s_setprio(1);
#pragma unroll
      for (int kc = 0; kc < 4; ++kc) {
        short8 B0 = *(const short8*)&ksmN[(s * 8 + kc * 2 + 0) * 512 + lane * 8];
        short8 B1 = *(const short8*)&ksmN[(s * 8 + kc * 2 + 1) * 512 + lane * 8];
        MFMA_B16(C0, A[kc][0], B0);
        MFMA_B16(C1, A[kc][1], B0);
        MFMA_B16(C1, A[kc][0], B1);
      }
      __builtin_amdgcn_s_setprio(0);
#pragma unroll
      for (int r = 0; r < 4; ++r) {
        float pv = __expf((C0[r] + C1[r]) * SCALE_F);
        lacc[r] += pv;
        unsigned short p0, p1;
        split2(pv, p0, p1);
        pbuf[w][0][quad * 4 + r][s * 16 + ln] = p0;
        pbuf[w][1][quad * 4 + r][s * 16 + ln] = p1;
      }
    }
    asm volatile("s_waitcnt lgkmcnt(0)" ::: "memory");  // flush pbuf writes
    __builtin_amdgcn_s_barrier();      // b3: all pbuf visible
    __builtin_amdgcn_sched_barrier(0);

    // ---- PV phase (wave w owns qsubs {qs0,qs0+1} x dts [dtb,dtb+4)) ----
    short8 P0a, P1a, P0b, P1b;
    {
      const unsigned short* pb;
      short4v lo, hi;
      pb = &pbuf[qs0][0][ln][quad * 8];
      lo = *(const short4v*)pb; hi = *(const short4v*)(pb + 4);
      P0a = __builtin_shufflevector(lo, hi, 0, 1, 2, 3, 4, 5, 6, 7);
      pb = &pbuf[qs0][1][ln][quad * 8];
      lo = *(const short4v*)pb; hi = *(const short4v*)(pb + 4);
      P1a = __builtin_shufflevector(lo, hi, 0, 1, 2, 3, 4, 5, 6, 7);
      pb = &pbuf[qs0 + 1][0][ln][quad * 8];
      lo = *(const short4v*)pb; hi = *(const short4v*)(pb + 4);
      P0b = __builtin_shufflevector(lo, hi, 0, 1, 2, 3, 4, 5, 6, 7);
      pb = &pbuf[qs0 + 1][1][ln][quad * 8];
      lo = *(const short4v*)pb; hi = *(const short4v*)(pb + 4);
      P1b = __builtin_shufflevector(lo, hi, 0, 1, 2, 3, 4, 5, 6, 7);
    }
    __builtin_amdgcn_s_setprio(1);
#pragma unroll
    for (int d2 = 0; d2 < 4; ++d2) {
      const int dt = dtb + d2;
      short8 V0 = *(const short8*)&vsm[0][dt * 16 + ln][quad * 8];
      short8 V1 = *(const short8*)&vsm[1][dt * 16 + ln][quad * 8];
      MFMA_B16(Oa[d2], P0a, V0);
      MFMA_B16(Oa[d2], P1a, V0);
      MFMA_B16(Oa[d2], P0a, V1);
      MFMA_B16(Ob[d2], P0b, V0);
      MFMA_B16(Ob[d2], P1b, V0);
      MFMA_B16(Ob[d2], P0b, V1);
    }
    __builtin_amdgcn_s_setprio(0);
  }

  // rl exchange: QK wave w produced lacc for q-subtile w.
#pragma unroll
  for (int r = 0; r < 4; ++r) {
    float l = lacc[r];
    l += __shfl_xor(l, 1);
    l += __shfl_xor(l, 2);
    l += __shfl_xor(l, 4);
    l += __shfl_xor(l, 8);
    float rl = 1.f / l;
    if (ln == 0) rls_sm[w][quad * 4 + r] = rl;
  }
  __syncthreads();

#pragma unroll
  for (int half = 0; half < 2; ++half) {
    const int qs = qs0 + half;
#pragma unroll
    for (int r = 0; r < 4; ++r) {
      float rlv = rls_sm[qs][quad * 4 + r];
      float* op =
          &out[(size_t)(h * SS + g * 192 + qs * 16 + quad * 4 + r) * DD];
#pragma unroll
      for (int d2 = 0; d2 < 4; ++d2) {
        float ov = half ? Ob[d2][r] : Oa[d2][r];
        op[(dtb + d2) * 16 + ln] = ov * rlv;
      }
    }
  }
}

// ---------------------------------------------------------------------------
extern "C" void kernel_launch(void* const* d_in, const int* in_sizes, int n_in,
                              void* d_out, int out_size, void* d_ws, size_t ws_size,
                              hipStream_t stream) {
  const float* q = (const float*)d_in[0];
  const float* k = (const float*)d_in[1];
  const float* v = (const float*)d_in[2];
  float* out = (float*)d_out;

  // Workspace (~81 MB): qsplit/ksplit bf16x3 fragment layout, lpart[4],
  // bs, inds, boundary scratch.
  const size_t SPLIT_ELEMS = (size_t)HH * NT * TCH * 8;   // 17,694,720 ushorts
  unsigned short* qsplit = (unsigned short*)d_ws;
  unsigned short* ksplit = qsplit + SPLIT_ELEMS;
  double* lpart = (double*)(ksplit + SPLIT_ELEMS);        // [4*HS]
  double* bs = lpart + 4 * (size_t)HS;                    // [HH*QGn*SS]
  int* inds = (int*)(bs + (size_t)HH * QGn * SS);         // [NROWS*TKn]
  double* bnd_val = (double*)(inds + (size_t)NROWS * TKn);// [NROWS*2]
  int* bnd_idx = (int*)(bnd_val + (size_t)NROWS * 2);     // [NROWS*2]
  int* rsel = bnd_idx + NROWS * 2;                        // [4] (unused, layout kept)
  double* rl_exact = (double*)(rsel + 4);                 // [192]

  presplit_kernel<<<dim3(NT, HH, 2), 1024, 0, stream>>>(q, k, qsplit, ksplit);
  stats_mfma<<<dim3(SS / 128, HH, 4), 256, 0, stream>>>(qsplit, ksplit, lpart);
  colsum_mfma<<<dim3(SS / 128, QGn, HH), 256, 0, stream>>>(qsplit, ksplit, lpart, bs);
  topk3_kernel<<<dim3(NROWS), 256, 0, stream>>>(bs, inds, bnd_val, bnd_idx);
  exact_rl_kernel<<<dim3(192), 256, 0, stream>>>(q, k, bnd_val, rl_exact);
  exact_pair_kernel<<<dim3(1), 256, 0, stream>>>(q, k, bnd_val, bnd_idx, rl_exact, inds);
  sparse_attn_mfma<<<dim3(QGn, HH), 768, 0, stream>>>(q, v, inds, ksplit, out);
}

// Round 11
// 702.816 us; speedup vs baseline: 1.0453x; 1.0453x over previous
//
#include <hip/hip_runtime.h>
#include <math.h>

// SparseDiffAttn: B=1, H=12, S=3840, D=128, BM=192 (QG=20), topk=1024.
// R21: revert R20's PV re-split (regressed 721->735: the 3rd barrier +
// lgkmcnt(0) pbuf flush per tile cost more than the halved V-reads saved;
// R19's wave-local pbuf self-consume lets the compiler use fine counted
// lgkmcnt). Keep R20 items 2+3: argmin launch deleted (exact_rl/exact_pair
// replicate the deterministic argmin reduction) + presplit 16B stores.
// sparse_attn == R19's 720.9us version verbatim. stats/colsum/topk3
// unchanged from R16 (scoring pinned at 59-60% MfmaUtil over 6 variants).
// All values bit-identical -> absmax must stay exactly 0.0009765625.

#define HH 12
#define SS 3840
#define DD 128
#define QGn 20
#define TKn 1024
#define NROWS (HH * QGn)
#define HS (HH * SS)
#define NT 60            // 64-row tiles per head
#define TCH 3072         // 16B chunks per tile (64 rows x 128 dims x 3 comps)
#define SCALE_D 0.08838834764831845
#define SCALE_F 0.08838834764831845f

typedef short short8 __attribute__((ext_vector_type(8)));
typedef short short4v __attribute__((ext_vector_type(4)));
typedef float f32x4 __attribute__((ext_vector_type(4)));

#define MFMA(a, b, c) __builtin_amdgcn_mfma_f32_16x16x32_bf16(a, b, c, 0, 0, 0)
#define MFMA_B16(c, a, b) \
  c = __builtin_amdgcn_mfma_f32_16x16x32_bf16(a, b, c, 0, 0, 0)

typedef __attribute__((address_space(3))) unsigned int lds_u32;
typedef const __attribute__((address_space(1))) unsigned int glb_u32;

__device__ __forceinline__ unsigned short bf_rne(float x) {
  unsigned u = __float_as_uint(x);
  u = (u + 0x7fffu + ((u >> 16) & 1u)) >> 16;
  return (unsigned short)u;
}
__device__ __forceinline__ float bf_f(unsigned short b) {
  return __uint_as_float(((unsigned)b) << 16);
}
__device__ __forceinline__ void split3(float f, unsigned short& a,
                                       unsigned short& b, unsigned short& c) {
  a = bf_rne(f);
  float r = f - bf_f(a);
  b = bf_rne(r);
  r = r - bf_f(b);
  c = bf_rne(r);
}
__device__ __forceinline__ void split2(float f, unsigned short& a,
                                       unsigned short& b) {
  a = bf_rne(f);
  float r = f - bf_f(a);
  b = bf_rne(r);
}
__device__ __forceinline__ short8 ldfrag(const unsigned short* base, int chunk) {
  return *(const short8*)&base[(size_t)chunk * 8];
}

// ---------------------------------------------------------------------------
// Kernel 0: presplit Q,K -> bf16 triples in fragment-chunk layout.
// R20: paired ushort4 stores merged into aligned 16B stores (kept).
// ---------------------------------------------------------------------------
__global__ __launch_bounds__(1024) void presplit_kernel(
    const float* __restrict__ q, const float* __restrict__ k,
    unsigned short* __restrict__ qsplit, unsigned short* __restrict__ ksplit) {
  const int t = threadIdx.x;
  const int lane = t & 63;
  const int u = t >> 6;
  const int kc = u & 3, kt = u >> 2;
  const int ln = lane & 15, quad = lane >> 4;
  const int c = blockIdx.x;
  const int h = blockIdx.y;
  const float* src = blockIdx.z ? k : q;
  unsigned short* dst = blockIdx.z ? ksplit : qsplit;

  const float* p =
      &src[(size_t)(h * SS + c * 64 + kt * 16 + ln) * DD + kc * 32 + quad * 8];
  float b8[8];
  *(float4*)&b8[0] = *(const float4*)&p[0];
  *(float4*)&b8[4] = *(const float4*)&p[4];
  __attribute__((aligned(16))) unsigned short f0[8], f1[8], f2[8];
#pragma unroll
  for (int e = 0; e < 8; ++e) split3(b8[e], f0[e], f1[e], f2[e]);
  size_t base =
      ((size_t)(h * NT + c) * TCH + ((kt * 4 + kc) * 3) * 64 + lane) * 8;
  *(uint4*)&dst[base + 0] = *(const uint4*)f0;
  *(uint4*)&dst[base + 512] = *(const uint4*)f1;        // cm=1: +64 chunks
  *(uint4*)&dst[base + 1024] = *(const uint4*)f2;       // cm=2: +128 chunks
}

// ---------------------------------------------------------------------------
// Kernel 1: partial softmax denominators. R16 structure (3-slot single-barrier
// tail-deferred pipeline), unchanged.
// ---------------------------------------------------------------------------
__global__ __launch_bounds__(256) void stats_mfma(
    const unsigned short* __restrict__ qsplit,
    const unsigned short* __restrict__ ksplit,
    double* __restrict__ lpart) {
  __shared__ __align__(16) unsigned short Bs[3][6144];  // 3 x 12 KiB slots
  const int t = threadIdx.x;
  const int w = t >> 6;
  const int lane = t & 63;
  const int ln = lane & 15;
  const int quad = lane >> 4;
  const int h = blockIdx.y;
  const int nq = blockIdx.z;
  const int q0 = blockIdx.x * 128 + w * 32;
  const int tq = blockIdx.x * 2 + (w >> 1);
  const int ktA = (w & 1) * 2;

  short8 A[2][4][3];
  {
    const unsigned short* qb = &qsplit[(size_t)(h * NT + tq) * TCH * 8];
#pragma unroll
    for (int s = 0; s < 2; ++s)
#pragma unroll
      for (int kc = 0; kc < 4; ++kc)
#pragma unroll
        for (int cm = 0; cm < 3; ++cm)
          A[s][kc][cm] =
              ldfrag(qb, (((ktA + s) * 4 + kc) * 3 + cm) * 64 + lane);
  }

  double racc[2][4];
#pragma unroll
  for (int s = 0; s < 2; ++s)
#pragma unroll
    for (int r = 0; r < 4; ++r) racc[s][r] = 0.0;

  // Quarter's key stream: 60 contiguous 12KB 16-key sub-tiles.
  // j = (c - nq*15)*4 + kt, same order as R10-R20 (bit-identical).
  const unsigned short* kq = &ksplit[(size_t)(h * NT + nq * 15) * TCH * 8];

#define STG_S(slot, j)                                                     \
  do {                                                                     \
    const unsigned short* src_ = kq + (size_t)(j) * 6144 + t * 8;          \
    __builtin_amdgcn_global_load_lds((glb_u32*)(src_),                     \
        (lds_u32*)&Bs[slot][w * 512], 16, 0, 0);                           \
    __builtin_amdgcn_global_load_lds((glb_u32*)(src_ + 2048),              \
        (lds_u32*)&Bs[slot][2048 + w * 512], 16, 0, 0);                    \
    __builtin_amdgcn_global_load_lds((glb_u32*)(src_ + 4096),              \
        (lds_u32*)&Bs[slot][4096 + w * 512], 16, 0, 0);                    \
  } while (0)

  const f32x4 z = {0.f, 0.f, 0.f, 0.f};
  f32x4 C[2][3];  // holds step j-1's scores at the top of step j

  // Prologue: tile 0 in flight.
  STG_S(0, 0);

  int cur = 0;
#pragma unroll 1
  for (int j = 0; j < 60; ++j) {
    __builtin_amdgcn_sched_barrier(0);
    if (j < 59) {
      const int nxt = (cur == 2) ? 0 : cur + 1;
      STG_S(nxt, j + 1);
      asm volatile("s_waitcnt vmcnt(3)" ::: "memory");  // own tile-j loads done
    } else {
      asm volatile("s_waitcnt vmcnt(0)" ::: "memory");
    }
    __builtin_amdgcn_s_barrier();  // all waves drained own tile-j loads
    __builtin_amdgcn_sched_barrier(0);
    __builtin_amdgcn_s_setprio(1);
    if (j > 0) {
      // deferred tail of step j-1 (same values, same racc order)
#pragma unroll
      for (int s = 0; s < 2; ++s)
#pragma unroll
        for (int r = 0; r < 4; ++r) {
          float sv = (C[s][0][r] + C[s][1][r]) + C[s][2][r];
          racc[s][r] += (double)__expf(sv * SCALE_F);
        }
    }
    const unsigned short* Bp = &Bs[cur][0];
#pragma unroll
    for (int kc = 0; kc < 4; ++kc) {
      short8 B0 = *(const short8*)&Bp[(kc * 3 + 0) * 512 + lane * 8];
      short8 B1 = *(const short8*)&Bp[(kc * 3 + 1) * 512 + lane * 8];
      short8 B2 = *(const short8*)&Bp[(kc * 3 + 2) * 512 + lane * 8];
#pragma unroll
      for (int s = 0; s < 2; ++s) {
        if (kc == 0) {
          C[s][0] = MFMA(A[s][0][0], B0, z);         // == 0 + A0B0
          C[s][1] = MFMA(A[s][0][0], B1, z);         // == 0 + A0B1
          C[s][1] = MFMA(A[s][0][1], B0, C[s][1]);
          C[s][0] = MFMA(A[s][0][1], B1, C[s][0]);
          C[s][2] = MFMA(A[s][0][2], B0, z);         // == 0 + A2B0
          C[s][2] = MFMA(A[s][0][0], B2, C[s][2]);
        } else {
          MFMA_B16(C[s][0], A[s][kc][0], B0);
          MFMA_B16(C[s][1], A[s][kc][0], B1);
          MFMA_B16(C[s][1], A[s][kc][1], B0);
          MFMA_B16(C[s][0], A[s][kc][1], B1);
          MFMA_B16(C[s][2], A[s][kc][2], B0);
          MFMA_B16(C[s][2], A[s][kc][0], B2);
        }
      }
    }
    __builtin_amdgcn_s_setprio(0);
    cur = (cur == 2) ? 0 : cur + 1;  // no end barrier: 3-slot rotation is safe
  }
#undef STG_S

  // final tail (step 59)
#pragma unroll
  for (int s = 0; s < 2; ++s)
#pragma unroll
    for (int r = 0; r < 4; ++r) {
      float sv = (C[s][0][r] + C[s][1][r]) + C[s][2][r];
      racc[s][r] += (double)__expf(sv * SCALE_F);
    }

#pragma unroll
  for (int s = 0; s < 2; ++s)
#pragma unroll
    for (int r = 0; r < 4; ++r) {
      double v = racc[s][r];
      v += __shfl_xor(v, 1);
      v += __shfl_xor(v, 2);
      v += __shfl_xor(v, 4);
      v += __shfl_xor(v, 8);
      if (ln == 0)
        lpart[(size_t)nq * HS + h * SS + q0 + s * 16 + quad * 4 + r] = v;
    }
}

// ---------------------------------------------------------------------------
// Kernel 2: bs colsums. R16 structure (3-slot single-barrier), unchanged.
// ---------------------------------------------------------------------------
__global__ __launch_bounds__(256) void colsum_mfma(
    const unsigned short* __restrict__ qsplit,
    const unsigned short* __restrict__ ksplit,
    const double* __restrict__ lpart, double* __restrict__ bs) {
  __shared__ double rls[192];
  __shared__ __align__(16) unsigned short As[3][6144];  // 3 x 12 KiB slots
  const int t = threadIdx.x;
  const int w = t >> 6;
  const int lane = t & 63;
  const int ln = lane & 15;
  const int quad = lane >> 4;
  const int h = blockIdx.z, g = blockIdx.y;
  const int k0 = blockIdx.x * 128 + w * 32;
  const int tk = blockIdx.x * 2 + (w >> 1);
  const int ktB = (w & 1) * 2;

  short8 Bk[2][4][3];
  {
    const unsigned short* kb = &ksplit[(size_t)(h * NT + tk) * TCH * 8];
#pragma unroll
    for (int s = 0; s < 2; ++s)
#pragma unroll
      for (int kc = 0; kc < 4; ++kc)
#pragma unroll
        for (int cm = 0; cm < 3; ++cm)
          Bk[s][kc][cm] =
              ldfrag(kb, (((ktB + s) * 4 + kc) * 3 + cm) * 64 + lane);
  }

  if (t < 192) {
    size_t qi = h * SS + g * 192 + t;
    rls[t] = 1.0 / (lpart[qi] + lpart[HS + qi] + lpart[2 * (size_t)HS + qi] +
                    lpart[3 * (size_t)HS + qi]);
  }
  __syncthreads();  // rls visible to all waves before staging loop

  double cacc[2] = {0.0, 0.0};

  // Group's query stream: 12 contiguous 12KB 16-query sub-tiles.
  // j = qc*4 + qt, same order as R10-R20 (bit-identical); qrow = 16*j.
  const unsigned short* qg = &qsplit[(size_t)(h * NT + g * 3) * TCH * 8];

#define STG_C(slot, j)                                                     \
  do {                                                                     \
    const unsigned short* src_ = qg + (size_t)(j) * 6144 + t * 8;          \
    __builtin_amdgcn_global_load_lds((glb_u32*)(src_),                     \
        (lds_u32*)&As[slot][w * 512], 16, 0, 0);                           \
    __builtin_amdgcn_global_load_lds((glb_u32*)(src_ + 2048),              \
        (lds_u32*)&As[slot][2048 + w * 512], 16, 0, 0);                    \
    __builtin_amdgcn_global_load_lds((glb_u32*)(src_ + 4096),              \
        (lds_u32*)&As[slot][4096 + w * 512], 16, 0, 0);                    \
  } while (0)

  const f32x4 z = {0.f, 0.f, 0.f, 0.f};
  f32x4 C[2][3];  // holds step j-1's scores at the top of step j

  // Prologue: tile 0 in flight.
  STG_C(0, 0);

  int cur = 0;
#pragma unroll 1
  for (int j = 0; j < 12; ++j) {
    __builtin_amdgcn_sched_barrier(0);
    if (j < 11) {
      const int nxt = (cur == 2) ? 0 : cur + 1;
      STG_C(nxt, j + 1);
      asm volatile("s_waitcnt vmcnt(3)" ::: "memory");  // own tile-j loads done
    } else {
      asm volatile("s_waitcnt vmcnt(0)" ::: "memory");
    }
    __builtin_amdgcn_s_barrier();
    __builtin_amdgcn_sched_barrier(0);
    __builtin_amdgcn_s_setprio(1);
    if (j > 0) {
      const int qprev = (j - 1) * 16;  // tail of step j-1
#pragma unroll
      for (int s = 0; s < 2; ++s)
#pragma unroll
        for (int r = 0; r < 4; ++r) {
          float p = __expf(((C[s][0][r] + C[s][1][r]) + C[s][2][r]) * SCALE_F);
          cacc[s] += (double)p * rls[qprev + quad * 4 + r];
        }
    }
    const unsigned short* Ap = &As[cur][0];
#pragma unroll
    for (int kc = 0; kc < 4; ++kc) {
      short8 A0 = *(const short8*)&Ap[(kc * 3 + 0) * 512 + lane * 8];
      short8 A1 = *(const short8*)&Ap[(kc * 3 + 1) * 512 + lane * 8];
      short8 A2 = *(const short8*)&Ap[(kc * 3 + 2) * 512 + lane * 8];
#pragma unroll
      for (int s = 0; s < 2; ++s) {
        if (kc == 0) {
          C[s][0] = MFMA(A0, Bk[s][0][0], z);        // == 0 + A0Bk0
          C[s][1] = MFMA(A1, Bk[s][0][0], z);        // == 0 + A1Bk0
          C[s][1] = MFMA(A0, Bk[s][0][1], C[s][1]);
          C[s][0] = MFMA(A1, Bk[s][0][1], C[s][0]);
          C[s][2] = MFMA(A2, Bk[s][0][0], z);        // == 0 + A2Bk0
          C[s][2] = MFMA(A0, Bk[s][0][2], C[s][2]);
        } else {
          MFMA_B16(C[s][0], A0, Bk[s][kc][0]);
          MFMA_B16(C[s][1], A1, Bk[s][kc][0]);
          MFMA_B16(C[s][1], A0, Bk[s][kc][1]);
          MFMA_B16(C[s][0], A1, Bk[s][kc][1]);
          MFMA_B16(C[s][2], A2, Bk[s][kc][0]);
          MFMA_B16(C[s][2], A0, Bk[s][kc][2]);
        }
      }
    }
    __builtin_amdgcn_s_setprio(0);
    cur = (cur == 2) ? 0 : cur + 1;  // no end barrier
  }
#undef STG_C

  // final tail (step 11, qrow = 176)
#pragma unroll
  for (int s = 0; s < 2; ++s)
#pragma unroll
    for (int r = 0; r < 4; ++r) {
      float p = __expf(((C[s][0][r] + C[s][1][r]) + C[s][2][r]) * SCALE_F);
      cacc[s] += (double)p * rls[176 + quad * 4 + r];
    }

#pragma unroll
  for (int s = 0; s < 2; ++s) {
    double v = cacc[s];
    v += __shfl_xor(v, 16);
    v += __shfl_xor(v, 32);
    if (quad == 0)
      bs[(size_t)(h * QGn + g) * SS + k0 + s * 16 + ln] = v;
  }
}

// ---------------------------------------------------------------------------
// Kernel 3: radix top-1024 + boundary capture (R16 parallel suffix-scan,
// unchanged).
// ---------------------------------------------------------------------------
__global__ __launch_bounds__(256) void topk3_kernel(
    const double* __restrict__ bs, int* __restrict__ inds,
    double* __restrict__ bnd_val, int* __restrict__ bnd_idx) {
  __shared__ unsigned long long u[SS];
  __shared__ int hist[256];
  __shared__ int sfx[256];
  __shared__ int s_bin, s_r;
  __shared__ int c_gt, c_eq;
  __shared__ unsigned long long rv[256];
  __shared__ int ri[256];
  const int t = threadIdx.x;
  const int row = blockIdx.x;
  const double* vals = bs + (size_t)row * SS;

  for (int i = t; i < SS; i += 256)
    u[i] = (unsigned long long)__double_as_longlong(vals[i]);

  unsigned long long pref = 0ull;
  int r = TKn;
  for (int shift = 56; shift >= 0; shift -= 8) {
    hist[t] = 0;
    __syncthreads();
    unsigned long long himask =
        (shift == 56) ? 0ull : (0xFFFFFFFFFFFFFFFFull << (shift + 8));
    for (int i = t; i < SS; i += 256) {
      unsigned long long uv = u[i];
      if ((uv & himask) == (pref & himask))
        atomicAdd(&hist[(int)((uv >> shift) & 255)], 1);
    }
    __syncthreads();
    // inclusive suffix scan of hist into sfx (Hillis-Steele, 8 steps)
    sfx[t] = hist[t];
    __syncthreads();
#pragma unroll
    for (int off = 1; off < 256; off <<= 1) {
      int v = (t + off < 256) ? sfx[t + off] : 0;
      __syncthreads();
      sfx[t] += v;
      __syncthreads();
    }
    // serial equivalent: highest bin b with S(b) >= r; s_r = r - S(b+1)
    {
      int St = sfx[t];
      int Sn = (t == 255) ? 0 : sfx[t + 1];
      if (St >= r && Sn < r) {
        s_bin = t;
        s_r = r - Sn;
      }
    }
    if (t == 0) {
      c_gt = 0;
      c_eq = 0;
    }
    __syncthreads();
    pref |= ((unsigned long long)s_bin) << shift;
    r = s_r;
    __syncthreads();
  }
  const int G = TKn - r;
  int* out = inds + (size_t)row * TKn;
  unsigned long long mb = 0ull;
  int mbi = -1;
  for (int i = t; i < SS; i += 256) {
    unsigned long long uv = u[i];
    if (uv > pref) {
      int p = atomicAdd(&c_gt, 1);
      out[p] = i;
    } else if (uv == pref) {
      int e = atomicAdd(&c_eq, 1);
      if (e < r) out[G + e] = i;
      if (e == r - 1) bnd_idx[row * 2 + 0] = i;
    } else if (uv > mb) {
      mb = uv;
      mbi = i;
    }
  }
  rv[t] = mb;
  ri[t] = mbi;
  __syncthreads();
  for (int s2 = 128; s2 > 0; s2 >>= 1) {
    if (t < s2 && rv[t + s2] > rv[t]) {
      rv[t] = rv[t + s2];
      ri[t] = ri[t + s2];
    }
    __syncthreads();
  }
  if (t == 0) {
    bnd_val[row * 2 + 0] = __longlong_as_double((long long)pref);
    bnd_val[row * 2 + 1] = __longlong_as_double((long long)rv[0]);
    bnd_idx[row * 2 + 1] = ri[0];
  }
}

// ---------------------------------------------------------------------------
// exact_rl: replicated argmin over 240 rows (identical reduction + tie-break
// as the deleted argmin_kernel; deterministic). Kept from R20.
// ---------------------------------------------------------------------------
__global__ __launch_bounds__(256) void exact_rl_kernel(
    const float* __restrict__ q, const float* __restrict__ k,
    const double* __restrict__ bnd_val, double* __restrict__ rl_exact) {
  __shared__ double gmin[256];
  __shared__ int grow[256];
  __shared__ double qd[DD];
  __shared__ double red[256];
  const int t = threadIdx.x;
  {
    double gv = 1e300;
    int rr = -1;
    if (t < NROWS) {
      gv = bnd_val[t * 2 + 0] - bnd_val[t * 2 + 1];
      rr = t;
    }
    gmin[t] = gv;
    grow[t] = rr;
    __syncthreads();
    for (int s2 = 128; s2 > 0; s2 >>= 1) {
      if (t < s2 && gmin[t + s2] < gmin[t]) {
        gmin[t] = gmin[t + s2];
        grow[t] = grow[t + s2];
      }
      __syncthreads();
    }
  }
  const int row = grow[0];
  const int h = row / QGn, g = row % QGn;
  const float* qp = &q[(size_t)(h * SS + g * 192 + blockIdx.x) * DD];
  if (t < DD) qd[t] = (double)qp[t];
  __syncthreads();
  double l = 0.0;
  for (int kk = t; kk < SS; kk += 256) {
    const float* kp = &k[(size_t)(h * SS + kk) * DD];
    double s = 0.0;
#pragma unroll 4
    for (int d = 0; d < DD; d += 4) {
      float4 kv = *(const float4*)&kp[d];
      s += qd[d] * (double)kv.x + qd[d + 1] * (double)kv.y +
           qd[d + 2] * (double)kv.z + qd[d + 3] * (double)kv.w;
    }
    l += exp(s * SCALE_D);
  }
  red[t] = l;
  __syncthreads();
  for (int s2 = 128; s2 > 0; s2 >>= 1) {
    if (t < s2) red[t] += red[t + s2];
    __syncthreads();
  }
  if (t == 0) rl_exact[blockIdx.x] = 1.0 / red[0];
}

// ---------------------------------------------------------------------------
// exact_pair: same replicated argmin; kept/drop from bnd_idx. Kept from R20.
// ---------------------------------------------------------------------------
__global__ __launch_bounds__(256) void exact_pair_kernel(
    const float* __restrict__ q, const float* __restrict__ k,
    const double* __restrict__ bnd_val, const int* __restrict__ bnd_idx,
    const double* __restrict__ rl_exact, int* __restrict__ inds) {
  __shared__ double gmin[256];
  __shared__ int grow[256];
  __shared__ double redX[256], redY[256];
  const int t = threadIdx.x;
  {
    double gv = 1e300;
    int rr = -1;
    if (t < NROWS) {
      gv = bnd_val[t * 2 + 0] - bnd_val[t * 2 + 1];
      rr = t;
    }
    gmin[t] = gv;
    grow[t] = rr;
    __syncthreads();
    for (int s2 = 128; s2 > 0; s2 >>= 1) {
      if (t < s2 && gmin[t + s2] < gmin[t]) {
        gmin[t] = gmin[t + s2];
        grow[t] = grow[t + s2];
      }
      __syncthreads();
    }
  }
  const int row = grow[0];
  const int kept = bnd_idx[row * 2 + 0], drop = bnd_idx[row * 2 + 1];
  const int h = row / QGn, g = row % QGn;
  double px = 0.0, py = 0.0;
  if (t < 192) {
    const float* qp = &q[(size_t)(h * SS + g * 192 + t) * DD];
    const float* kx = &k[(size_t)(h * SS + kept) * DD];
    const float* ky = &k[(size_t)(h * SS + drop) * DD];
    double sx = 0.0, sy = 0.0;
#pragma unroll 4
    for (int d = 0; d < DD; ++d) {
      double qv = (double)qp[d];
      sx += qv * (double)kx[d];
      sy += qv * (double)ky[d];
    }
    double rv = rl_exact[t];
    px = exp(sx * SCALE_D) * rv;
    py = exp(sy * SCALE_D) * rv;
  }
  redX[t] = px;
  redY[t] = py;
  __syncthreads();
  for (int s2 = 128; s2 > 0; s2 >>= 1) {
    if (t < s2) { redX[t] += redX[t + s2]; redY[t] += redY[t + s2]; }
    __syncthreads();
  }
  if (t == 0)
    inds[(size_t)row * TKn + (TKn - 1)] = (redX[0] <= redY[0]) ? kept : drop;
}

// ---------------------------------------------------------------------------
// Kernel 4: MFMA sparse gathered attention — R19 version verbatim (720.9us).
// One 768-thread block per (g,h); waves 0-3 stage (K gll from ksplit, V
// gather/split2/scatter, reg prefetch, counted vmcnt(4)); all 12 waves
// compute their 16 q-rows; pbuf wave-local (self-consume, no extra barrier).
// ---------------------------------------------------------------------------
__global__ __launch_bounds__(768, 3) void sparse_attn_mfma(
    const float* __restrict__ q, const float* __restrict__ v,
    const int* __restrict__ inds, const unsigned short* __restrict__ ksplit,
    float* __restrict__ out) {
  __shared__ __align__(16) unsigned short ksmN[16 * 512];   // 16 KB
  __shared__ __align__(16) unsigned short vsm[2][128][40];  // 20 KB
  __shared__ __align__(16) unsigned short pbuf[12][2][16][36];  // 27 KB
  const int t = threadIdx.x;
  const int w = t >> 6;            // 12 waves; waves 0-3 stage
  const int lane = t & 63;
  const int ln = lane & 15;
  const int quad = lane >> 4;
  const int g = blockIdx.x, h = blockIdx.y;
  const int* ip = &inds[(size_t)(h * QGn + g) * TKn];
  const unsigned short* kbh = &ksplit[(size_t)(h * NT) * (TCH * 8)];

  short8 A[4][2];
  {
    const float* qp =
        &q[(size_t)(h * SS + g * 192 + w * 16 + ln) * DD + quad * 8];
#pragma unroll
    for (int kc = 0; kc < 4; ++kc) {
      float b8[8];
      *(float4*)&b8[0] = *(const float4*)&qp[kc * 32];
      *(float4*)&b8[4] = *(const float4*)&qp[kc * 32 + 4];
      short8 f0, f1;
#pragma unroll
      for (int e = 0; e < 8; ++e) {
        unsigned short x0, x1;
        split2(b8[e], x0, x1);
        f0[e] = (short)x0; f1[e] = (short)x1;
      }
      A[kc][0] = f0; A[kc][1] = f1;
    }
  }

  f32x4 O[8];
#pragma unroll
  for (int dt = 0; dt < 8; ++dt) O[dt] = (f32x4){0.f, 0.f, 0.f, 0.f};
  float lacc[4] = {0.f, 0.f, 0.f, 0.f};

  const int kk = t >> 3;   // staging V row (valid for t < 256)
  const int sub = t & 7;
  const int sW = w >> 1;   // staging K subtile (waves 0-3)
  const int c0 = w * 4;    // first K chunk staged by this wave

  // Prologue (staging waves only): tile-0 staging key + V rows into regs.
  int gkA = 0;
  float4 rv4[4];
  if (w < 4) {
    gkA = ip[sW * 16 + ln];
    int gkV = ip[kk];
    const float* vp = &v[(size_t)(h * SS + gkV) * DD + sub * 16];
#pragma unroll
    for (int e4 = 0; e4 < 4; ++e4) rv4[e4] = *(const float4*)&vp[e4 * 4];
  }

  for (int kt = 0; kt < TKn; kt += 32) {
    __builtin_amdgcn_s_barrier();      // prev tile's LDS reads retired
    __builtin_amdgcn_sched_barrier(0);
    if (w < 4) {
      const bool more = (kt + 32 < TKn);
      int gkVn = 0, gkAn = 0;
      if (more) {
        gkVn = ip[kt + 32 + kk];              // next-tile V row
        gkAn = ip[kt + 32 + sW * 16 + ln];    // next-tile staging key
      }
      // K fragment staging: ksplit -> LDS, per-lane src, lane-linear dest.
      {
        const unsigned short* rowp = kbh + (size_t)(gkA >> 6) * (TCH * 8) +
                                     ((gkA & 15) + 16 * quad) * 8;
        const int ktile = (gkA >> 4) & 3;
#pragma unroll
        for (int i = 0; i < 4; ++i) {
          const int c16 = c0 + i;
          const int kc = (c16 >> 1) & 3;
          const int cm = c16 & 1;
          __builtin_amdgcn_global_load_lds(
              (glb_u32*)(rowp + ((ktile * 4 + kc) * 3 + cm) * 512),
              (lds_u32*)&ksmN[c16 * 512], 16, 0, 0);
        }
      }
      // V write from prefetched regs (split2 values identical).
#pragma unroll
      for (int e4 = 0; e4 < 4; ++e4) {
        float4 vv = rv4[e4];
        ushort4 v0, v1;
        split2(vv.x, v0.x, v1.x);
        split2(vv.y, v0.y, v1.y);
        split2(vv.z, v0.z, v1.z);
        split2(vv.w, v0.w, v1.w);
        int d0 = sub * 16 + e4 * 4;
        vsm[0][d0 + 0][kk] = v0.x; vsm[1][d0 + 0][kk] = v1.x;
        vsm[0][d0 + 1][kk] = v0.y; vsm[1][d0 + 1][kk] = v1.y;
        vsm[0][d0 + 2][kk] = v0.z; vsm[1][d0 + 2][kk] = v1.z;
        vsm[0][d0 + 3][kk] = v0.w; vsm[1][d0 + 3][kk] = v1.w;
      }
      // Issue next tile's V gather; counted wait keeps it in flight.
      if (more) {
        const float* vp = &v[(size_t)(h * SS + gkVn) * DD + sub * 16];
#pragma unroll
        for (int e4 = 0; e4 < 4; ++e4) rv4[e4] = *(const float4*)&vp[e4 * 4];
        asm volatile("s_waitcnt vmcnt(4) lgkmcnt(0)" ::: "memory");
        gkA = gkAn;
      } else {
        asm volatile("s_waitcnt vmcnt(0) lgkmcnt(0)" ::: "memory");
      }
    }
    __builtin_amdgcn_s_barrier();      // ksmN + vsm staged, all 12 waves
    __builtin_amdgcn_sched_barrier(0);

#pragma unroll
    for (int s = 0; s < 2; ++s) {
      f32x4 C0 = {0.f, 0.f, 0.f, 0.f};
      f32x4 C1 = C0;
      __builtin_amdgcn_s_setprio(1);
#pragma unroll
      for (int kc = 0; kc < 4; ++kc) {
        short8 B0 = *(const short8*)&ksmN[(s * 8 + kc * 2 + 0) * 512 + lane * 8];
        short8 B1 = *(const short8*)&ksmN[(s * 8 + kc * 2 + 1) * 512 + lane * 8];
        MFMA_B16(C0, A[kc][0], B0);
        MFMA_B16(C1, A[kc][1], B0);
        MFMA_B16(C1, A[kc][0], B1);
      }
      __builtin_amdgcn_s_setprio(0);
#pragma unroll
      for (int r = 0; r < 4; ++r) {
        float pv = __expf((C0[r] + C1[r]) * SCALE_F);
        lacc[r] += pv;
        unsigned short p0, p1;
        split2(pv, p0, p1);
        pbuf[w][0][quad * 4 + r][s * 16 + ln] = p0;
        pbuf[w][1][quad * 4 + r][s * 16 + ln] = p1;
      }
    }
    short8 P0, P1;
    {
      const unsigned short* pb0 = &pbuf[w][0][ln][quad * 8];
      const unsigned short* pb1 = &pbuf[w][1][ln][quad * 8];
      short4v lo0 = *(const short4v*)pb0;
      short4v hi0 = *(const short4v*)(pb0 + 4);
      short4v lo1 = *(const short4v*)pb1;
      short4v hi1 = *(const short4v*)(pb1 + 4);
      P0 = __builtin_shufflevector(lo0, hi0, 0, 1, 2, 3, 4, 5, 6, 7);
      P1 = __builtin_shufflevector(lo1, hi1, 0, 1, 2, 3, 4, 5, 6, 7);
    }
    __builtin_amdgcn_s_setprio(1);
#pragma unroll
    for (int dt = 0; dt < 8; ++dt) {
      short8 V0 = *(const short8*)&vsm[0][dt * 16 + ln][quad * 8];
      short8 V1 = *(const short8*)&vsm[1][dt * 16 + ln][quad * 8];
      MFMA_B16(O[dt], P0, V0);
      MFMA_B16(O[dt], P1, V0);
      MFMA_B16(O[dt], P0, V1);
    }
    __builtin_amdgcn_s_setprio(0);
  }

#pragma unroll
  for (int r = 0; r < 4; ++r) {
    float l = lacc[r];
    l += __shfl_xor(l, 1);
    l += __shfl_xor(l, 2);
    l += __shfl_xor(l, 4);
    l += __shfl_xor(l, 8);
    float rl = 1.f / l;
    float* op =
        &out[(size_t)(h * SS + g * 192 + w * 16 + quad * 4 + r) * DD];
#pragma unroll
    for (int dt = 0; dt < 8; ++dt) op[dt * 16 + ln] = O[dt][r] * rl;
  }
}

// ---------------------------------------------------------------------------
extern "C" void kernel_launch(void* const* d_in, const int* in_sizes, int n_in,
                              void* d_out, int out_size, void* d_ws, size_t ws_size,
                              hipStream_t stream) {
  const float* q = (const float*)d_in[0];
  const float* k = (const float*)d_in[1];
  const float* v = (const float*)d_in[2];
  float* out = (float*)d_out;

  // Workspace (~81 MB): qsplit/ksplit bf16x3 fragment layout, lpart[4],
  // bs, inds, boundary scratch.
  const size_t SPLIT_ELEMS = (size_t)HH * NT * TCH * 8;   // 17,694,720 ushorts
  unsigned short* qsplit = (unsigned short*)d_ws;
  unsigned short* ksplit = qsplit + SPLIT_ELEMS;
  double* lpart = (double*)(ksplit + SPLIT_ELEMS);        // [4*HS]
  double* bs = lpart + 4 * (size_t)HS;                    // [HH*QGn*SS]
  int* inds = (int*)(bs + (size_t)HH * QGn * SS);         // [NROWS*TKn]
  double* bnd_val = (double*)(inds + (size_t)NROWS * TKn);// [NROWS*2]
  int* bnd_idx = (int*)(bnd_val + (size_t)NROWS * 2);     // [NROWS*2]
  int* rsel = bnd_idx + NROWS * 2;                        // [4] (unused, layout kept)
  double* rl_exact = (double*)(rsel + 4);                 // [192]

  presplit_kernel<<<dim3(NT, HH, 2), 1024, 0, stream>>>(q, k, qsplit, ksplit);
  stats_mfma<<<dim3(SS / 128, HH, 4), 256, 0, stream>>>(qsplit, ksplit, lpart);
  colsum_mfma<<<dim3(SS / 128, QGn, HH), 256, 0, stream>>>(qsplit, ksplit, lpart, bs);
  topk3_kernel<<<dim3(NROWS), 256, 0, stream>>>(bs, inds, bnd_val, bnd_idx);
  exact_rl_kernel<<<dim3(192), 256, 0, stream>>>(q, k, bnd_val, rl_exact);
  exact_pair_kernel<<<dim3(1), 256, 0, stream>>>(q, k, bnd_val, bnd_idx, rl_exact, inds);
  sparse_attn_mfma<<<dim3(QGn, HH), 768, 0, stream>>>(q, v, inds, ksplit, out);
}